// Round 1
// baseline (626.690 us; speedup 1.0000x reference)
//
#include <hip/hip_runtime.h>
#include <stdint.h>
#include <stddef.h>

// IEEE-exact ops, no FMA contraction: we must reproduce the reference's f32
// arithmetic (binary labels, absmax threshold 2e-2 => exact label match).
#pragma clang fp contract(off)

#define HH 512
#define WW 512
#define HW_ 262144           // H*W
#define FEAT_BSTRIDE (256*HW_) // feature batch stride (C=256)

// normalize+quantize exactly like the reference:
// clip(floor((f-mn)/(mx-mn+1e-12)*255), 0, 255)
__device__ __forceinline__ float quantf(float f, float mn, float denom) {
  float v = (f - mn) / denom * 255.0f;
  v = floorf(v);
  return fminf(fmaxf(v, 0.0f), 255.0f);
}

// trimap geometry: bh=bw=51, center rows/cols [230,281)
__device__ __forceinline__ bool is_center(int y, int x) {
  return (y >= 230) & (y < 281) & (x >= 230) & (x < 281);
}
__device__ __forceinline__ bool is_border(int y, int x) {
  return (y < 51) | (y >= 461) | (x < 51) | (x >= 461);
}

// K1: per-batch min/max partials over the first 3 channel planes
// (channels 0..2 are contiguous: 786432 floats = 196608 float4 per batch;
//  128 blocks/batch -> 1536 float4/block -> 6/thread)
__global__ __launch_bounds__(256) void k_minmax(const float* __restrict__ feat,
                                                float2* __restrict__ mm) {
  int blk = blockIdx.x, tid = threadIdx.x;
  int b = blk >> 7, ib = blk & 127;
  const float4* base =
      reinterpret_cast<const float4*>(feat + (size_t)b * FEAT_BSTRIDE) + (size_t)ib * 1536;
  float mn = 3.4e38f, mx = -3.4e38f;
#pragma unroll
  for (int j = 0; j < 6; j++) {
    float4 v = base[tid + j * 256];
    mn = fminf(mn, fminf(fminf(v.x, v.y), fminf(v.z, v.w)));
    mx = fmaxf(mx, fmaxf(fmaxf(v.x, v.y), fmaxf(v.z, v.w)));
  }
  __shared__ float smn[256], smx[256];
  smn[tid] = mn; smx[tid] = mx;
  __syncthreads();
  for (int s = 128; s >= 1; s >>= 1) {
    if (tid < s) {
      smn[tid] = fminf(smn[tid], smn[tid + s]);
      smx[tid] = fmaxf(smx[tid], smx[tid + s]);
    }
    __syncthreads();
  }
  if (tid == 0) mm[blk] = make_float2(smn[0], smx[0]);
}

// K2: init alpha from mask+trimap; accumulate exact-int partials of
// slot0 fg sums (img_c*alpha, count) and per-channel totals.
__global__ __launch_bounds__(256) void k_init(const float* __restrict__ feat,
                                              const int* __restrict__ mask,
                                              const float2* __restrict__ mm,
                                              uint8_t* __restrict__ alphaA,
                                              int4* __restrict__ totals,
                                              int4* __restrict__ slot0) {
  int blk = blockIdx.x, tid = threadIdx.x;
  int b = blk >> 7;
  __shared__ float smn[128], smx[128];
  if (tid < 128) { float2 v = mm[b * 128 + tid]; smn[tid] = v.x; smx[tid] = v.y; }
  __syncthreads();
  for (int s = 64; s >= 1; s >>= 1) {
    if (tid < s) {
      smn[tid] = fminf(smn[tid], smn[tid + s]);
      smx[tid] = fmaxf(smx[tid], smx[tid + s]);
    }
    __syncthreads();
  }
  float mn = smn[0];
  float denom = (smx[0] - mn) + 1e-12f;  // f32, matches reference (+1e-12 is a no-op in f32)
  const float* fb = feat + (size_t)b * FEAT_BSTRIDE;
  int a0 = 0, a1 = 0, a2 = 0, a3 = 0, t0 = 0, t1 = 0, t2 = 0;
#pragma unroll
  for (int j = 0; j < 8; j++) {
    int p = blk * 2048 + tid + j * 256;
    int pb = p & (HW_ - 1);
    int y = pb >> 9, x = pb & 511;
    int r  = (int)quantf(fb[pb], mn, denom);
    int g  = (int)quantf(fb[HW_ + pb], mn, denom);
    int bl = (int)quantf(fb[2 * HW_ + pb], mn, denom);
    int a;
    if (is_center(y, x)) a = 1;
    else if (is_border(y, x)) a = 0;
    else a = (mask[p] == 1) ? 1 : 0;
    alphaA[p] = (uint8_t)a;
    a0 += r * a; a1 += g * a; a2 += bl * a; a3 += a;
    t0 += r; t1 += g; t2 += bl;
  }
  __shared__ int red[256][8];
  red[tid][0] = a0; red[tid][1] = a1; red[tid][2] = a2; red[tid][3] = a3;
  red[tid][4] = t0; red[tid][5] = t1; red[tid][6] = t2; red[tid][7] = 0;
  __syncthreads();
  for (int s = 128; s >= 1; s >>= 1) {
    if (tid < s) {
#pragma unroll
      for (int j = 0; j < 7; j++) red[tid][j] += red[tid + s][j];
    }
    __syncthreads();
  }
  if (tid == 0) {
    slot0[blk]  = make_int4(red[0][0], red[0][1], red[0][2], red[0][3]);
    totals[blk] = make_int4(red[0][4], red[0][5], red[0][6], 0);
  }
}

// K3..K7: one ICM iteration. Redundant per-block deterministic reduce of the
// batch's 128 partials -> means; then relabel + accumulate next slot partials.
__global__ __launch_bounds__(256) void k_relabel(const float* __restrict__ feat,
                                                 const uint8_t* __restrict__ ain,
                                                 uint8_t* __restrict__ aout,
                                                 const float2* __restrict__ mm,
                                                 const int4* __restrict__ totals,
                                                 const int4* __restrict__ slotIn,
                                                 int4* __restrict__ slotOut,
                                                 float* __restrict__ out,
                                                 int finalIter) {
  int blk = blockIdx.x, tid = threadIdx.x;
  int b = blk >> 7;
  __shared__ float smn[128], smx[128];
  __shared__ int red[128][8];
  if (tid < 128) {
    float2 v = mm[b * 128 + tid]; smn[tid] = v.x; smx[tid] = v.y;
    int4 s = slotIn[b * 128 + tid];
    int4 t = totals[b * 128 + tid];
    red[tid][0] = s.x; red[tid][1] = s.y; red[tid][2] = s.z; red[tid][3] = s.w;
    red[tid][4] = t.x; red[tid][5] = t.y; red[tid][6] = t.z; red[tid][7] = 0;
  }
  __syncthreads();
  for (int s = 64; s >= 1; s >>= 1) {
    if (tid < s) {
      smn[tid] = fminf(smn[tid], smn[tid + s]);
      smx[tid] = fmaxf(smx[tid], smx[tid + s]);
#pragma unroll
      for (int j = 0; j < 7; j++) red[tid][j] += red[tid + s][j];
    }
    __syncthreads();
  }
  __shared__ float fmv[3], bmv[3];
  if (tid == 0) {
    int cnt = red[0][3];
    float fden = (float)cnt + 1e-6f;
    float bden = (float)(HW_ - cnt) + 1e-6f;
#pragma unroll
    for (int c = 0; c < 3; c++) {
      fmv[c] = (float)red[0][c] / fden;                 // fg_mean (f32 div of exact sums)
      bmv[c] = (float)(red[0][4 + c] - red[0][c]) / bden; // bg_mean = (total - fg)/nbg
    }
  }
  __syncthreads();
  float f0 = fmv[0], f1 = fmv[1], f2 = fmv[2];
  float g0 = bmv[0], g1 = bmv[1], g2 = bmv[2];
  float mn = smn[0];
  float denom = (smx[0] - smn[0]) + 1e-12f;
  const float* fb = feat + (size_t)b * FEAT_BSTRIDE;
  int a0 = 0, a1 = 0, a2 = 0, a3 = 0;
#pragma unroll
  for (int j = 0; j < 8; j++) {
    int p = blk * 2048 + tid + j * 256;
    int pb = p & (HW_ - 1);
    int y = pb >> 9, x = pb & 511;
    float i0 = quantf(fb[pb], mn, denom);
    float i1 = quantf(fb[HW_ + pb], mn, denom);
    float i2 = quantf(fb[2 * HW_ + pb], mn, denom);
    // 4-neighbor mean with edge replication
    int up = ain[p - (y > 0 ? WW : 0)];
    int dn = ain[p + (y < HH - 1 ? WW : 0)];
    int lf = ain[p - (x > 0 ? 1 : 0)];
    int rt = ain[p + (x < WW - 1 ? 1 : 0)];
    float nb = (float)(((up + dn) + lf) + rt) * 0.25f;      // exact in f32
    float pair = 50.0f * ((2.0f * nb) - 1.0f);               // exact in f32
    float t0 = i0 - f0, t1 = i1 - f1, t2 = i2 - f2;
    float df = ((t0 * t0) + (t1 * t1)) + (t2 * t2);
    float u0 = i0 - g0, u1 = i1 - g1, u2 = i2 - g2;
    float db = ((u0 * u0) + (u1 * u1)) + (u2 * u2);
    float score = (db - df) + pair;
    int a;
    if (is_center(y, x)) a = 1;           // fixed FG
    else if (is_border(y, x)) a = 0;      // fixed BG
    else a = (score > 0.0f) ? 1 : 0;
    aout[p] = (uint8_t)a;
    if (finalIter) out[p] = (float)a;
    int ri = (int)i0, gi = (int)i1, bi = (int)i2;
    a0 += ri * a; a1 += gi * a; a2 += bi * a; a3 += a;
  }
  __shared__ int red2[256][4];
  red2[tid][0] = a0; red2[tid][1] = a1; red2[tid][2] = a2; red2[tid][3] = a3;
  __syncthreads();
  for (int s = 128; s >= 1; s >>= 1) {
    if (tid < s) {
#pragma unroll
      for (int j = 0; j < 4; j++) red2[tid][j] += red2[tid + s][j];
    }
    __syncthreads();
  }
  if (tid == 0) slotOut[blk] = make_int4(red2[0][0], red2[0][1], red2[0][2], red2[0][3]);
}

extern "C" void kernel_launch(void* const* d_in, const int* in_sizes, int n_in,
                              void* d_out, int out_size, void* d_ws, size_t ws_size,
                              hipStream_t stream) {
  const float* feat = (const float*)d_in[0];   // (2,256,512,512) f32
  const int*   mask = (const int*)d_in[1];     // (2,512,512) i32
  float* out = (float*)d_out;                  // (2,512,512) f32

  // ws layout (~1.05 MB total; everything rewritten each launch, poison-safe):
  char* ws = (char*)d_ws;
  uint8_t* aA     = (uint8_t*)(ws);                 // 524288
  uint8_t* aB     = (uint8_t*)(ws + 524288);        // 524288
  float2*  mm     = (float2*)(ws + 1048576);        // 256 * 8B
  int4*    totals = (int4*)(ws + 1050624);          // 256 * 16B
  int4*    slots  = (int4*)(ws + 1054720);          // 6 * 256 * 16B

  k_minmax<<<256, 256, 0, stream>>>(feat, mm);
  k_init<<<256, 256, 0, stream>>>(feat, mask, mm, aA, totals, slots /*slot0*/);

  uint8_t* ain = aA;
  uint8_t* aout_buf = aB;
  for (int k = 0; k < 5; k++) {
    k_relabel<<<256, 256, 0, stream>>>(feat, ain, aout_buf, mm, totals,
                                       slots + (size_t)k * 256,
                                       slots + (size_t)(k + 1) * 256,
                                       out, (k == 4) ? 1 : 0);
    uint8_t* tmp = ain; ain = aout_buf; aout_buf = tmp;
  }
}

// Round 2
// 611.696 us; speedup vs baseline: 1.0245x; 1.0245x over previous
//
#include <hip/hip_runtime.h>
#include <stdint.h>
#include <stddef.h>

// IEEE-exact ops, no FMA contraction: we must reproduce the reference's f32
// arithmetic (binary labels, absmax threshold 2e-2 => exact label match).
#pragma clang fp contract(off)

#define HH 512
#define WW 512
#define HW_ 262144             // H*W
#define FEAT_BSTRIDE (256*HW_) // feature batch stride (C=256)

// normalize+quantize exactly like the reference:
// clip(floor((f-mn)/(mx-mn+1e-12)*255), 0, 255)
__device__ __forceinline__ float quantf(float f, float mn, float denom) {
  float v = (f - mn) / denom * 255.0f;
  v = floorf(v);
  return fminf(fmaxf(v, 0.0f), 255.0f);
}

// trimap geometry: bh=bw=51, center rows/cols [230,281)
__device__ __forceinline__ bool is_center(int y, int x) {
  return (y >= 230) & (y < 281) & (x >= 230) & (x < 281);
}
__device__ __forceinline__ bool is_border(int y, int x) {
  return (y < 51) | (y >= 461) | (x < 51) | (x >= 461);
}

// K1: per-batch min/max partials over the first 3 channel planes
__global__ __launch_bounds__(256) void k_minmax(const float* __restrict__ feat,
                                                float2* __restrict__ mm) {
  int blk = blockIdx.x, tid = threadIdx.x;
  int b = blk >> 7, ib = blk & 127;
  const float4* base =
      reinterpret_cast<const float4*>(feat + (size_t)b * FEAT_BSTRIDE) + (size_t)ib * 1536;
  float mn = 3.4e38f, mx = -3.4e38f;
#pragma unroll
  for (int j = 0; j < 6; j++) {
    float4 v = base[tid + j * 256];
    mn = fminf(mn, fminf(fminf(v.x, v.y), fminf(v.z, v.w)));
    mx = fmaxf(mx, fmaxf(fmaxf(v.x, v.y), fmaxf(v.z, v.w)));
  }
  __shared__ float smn[256], smx[256];
  smn[tid] = mn; smx[tid] = mx;
  __syncthreads();
  for (int s = 128; s >= 1; s >>= 1) {
    if (tid < s) {
      smn[tid] = fminf(smn[tid], smn[tid + s]);
      smx[tid] = fmaxf(smx[tid], smx[tid + s]);
    }
    __syncthreads();
  }
  if (tid == 0) mm[blk] = make_float2(smn[0], smx[0]);
}

// K2: quantize first-3-channel image to packed u32 RGB (exact bytes 0..255),
// init alpha from mask+trimap; accumulate exact-int partials of slot0 fg sums
// and per-channel totals.
__global__ __launch_bounds__(256) void k_init(const float* __restrict__ feat,
                                              const int* __restrict__ mask,
                                              const float2* __restrict__ mm,
                                              uint32_t* __restrict__ packed,
                                              uint8_t* __restrict__ alphaA,
                                              int4* __restrict__ totals,
                                              int4* __restrict__ slot0) {
  int blk = blockIdx.x, tid = threadIdx.x;
  int b = blk >> 7;
  __shared__ float smn[128], smx[128];
  if (tid < 128) { float2 v = mm[b * 128 + tid]; smn[tid] = v.x; smx[tid] = v.y; }
  __syncthreads();
  for (int s = 64; s >= 1; s >>= 1) {
    if (tid < s) {
      smn[tid] = fminf(smn[tid], smn[tid + s]);
      smx[tid] = fmaxf(smx[tid], smx[tid + s]);
    }
    __syncthreads();
  }
  float mn = smn[0];
  float denom = (smx[0] - mn) + 1e-12f;  // f32, matches reference
  const float* fb = feat + (size_t)b * FEAT_BSTRIDE;
  int a0 = 0, a1 = 0, a2 = 0, a3 = 0, t0 = 0, t1 = 0, t2 = 0;
#pragma unroll
  for (int j = 0; j < 8; j++) {
    int p = blk * 2048 + tid + j * 256;
    int pb = p & (HW_ - 1);
    int y = pb >> 9, x = pb & 511;
    int r  = (int)quantf(fb[pb], mn, denom);
    int g  = (int)quantf(fb[HW_ + pb], mn, denom);
    int bl = (int)quantf(fb[2 * HW_ + pb], mn, denom);
    packed[p] = (uint32_t)r | ((uint32_t)g << 8) | ((uint32_t)bl << 16);
    int a;
    if (is_center(y, x)) a = 1;
    else if (is_border(y, x)) a = 0;
    else a = (mask[p] == 1) ? 1 : 0;
    alphaA[p] = (uint8_t)a;
    a0 += r * a; a1 += g * a; a2 += bl * a; a3 += a;
    t0 += r; t1 += g; t2 += bl;
  }
  __shared__ int red[256][8];
  red[tid][0] = a0; red[tid][1] = a1; red[tid][2] = a2; red[tid][3] = a3;
  red[tid][4] = t0; red[tid][5] = t1; red[tid][6] = t2; red[tid][7] = 0;
  __syncthreads();
  for (int s = 128; s >= 1; s >>= 1) {
    if (tid < s) {
#pragma unroll
      for (int j = 0; j < 7; j++) red[tid][j] += red[tid + s][j];
    }
    __syncthreads();
  }
  if (tid == 0) {
    slot0[blk]  = make_int4(red[0][0], red[0][1], red[0][2], red[0][3]);
    totals[blk] = make_int4(red[0][4], red[0][5], red[0][6], 0);
  }
}

// K3..K7: one ICM iteration from the packed image. Redundant per-block
// deterministic reduce of the batch's 128 partials -> means; relabel;
// accumulate next slot partials. Bytes->float is exact, so scores are
// bit-identical to recomputing the quantization.
__global__ __launch_bounds__(256) void k_relabel(const uint32_t* __restrict__ packed,
                                                 const uint8_t* __restrict__ ain,
                                                 uint8_t* __restrict__ aout,
                                                 const int4* __restrict__ totals,
                                                 const int4* __restrict__ slotIn,
                                                 int4* __restrict__ slotOut,
                                                 float* __restrict__ out,
                                                 int finalIter) {
  int blk = blockIdx.x, tid = threadIdx.x;
  int b = blk >> 7;
  __shared__ int red[128][8];
  if (tid < 128) {
    int4 s = slotIn[b * 128 + tid];
    int4 t = totals[b * 128 + tid];
    red[tid][0] = s.x; red[tid][1] = s.y; red[tid][2] = s.z; red[tid][3] = s.w;
    red[tid][4] = t.x; red[tid][5] = t.y; red[tid][6] = t.z; red[tid][7] = 0;
  }
  __syncthreads();
  for (int s = 64; s >= 1; s >>= 1) {
    if (tid < s) {
#pragma unroll
      for (int j = 0; j < 7; j++) red[tid][j] += red[tid + s][j];
    }
    __syncthreads();
  }
  __shared__ float fmv[3], bmv[3];
  if (tid == 0) {
    int cnt = red[0][3];
    float fden = (float)cnt + 1e-6f;
    float bden = (float)(HW_ - cnt) + 1e-6f;
#pragma unroll
    for (int c = 0; c < 3; c++) {
      fmv[c] = (float)red[0][c] / fden;                   // fg_mean
      bmv[c] = (float)(red[0][4 + c] - red[0][c]) / bden; // bg_mean = (total-fg)/nbg
    }
  }
  __syncthreads();
  float f0 = fmv[0], f1 = fmv[1], f2 = fmv[2];
  float g0 = bmv[0], g1 = bmv[1], g2 = bmv[2];
  int a0 = 0, a1 = 0, a2 = 0, a3 = 0;
#pragma unroll
  for (int j = 0; j < 8; j++) {
    int p = blk * 2048 + tid + j * 256;
    int pb = p & (HW_ - 1);
    int y = pb >> 9, x = pb & 511;
    uint32_t rgb = packed[p];
    int ri = (int)(rgb & 255u);
    int gi = (int)((rgb >> 8) & 255u);
    int bi = (int)((rgb >> 16) & 255u);
    float i0 = (float)ri, i1 = (float)gi, i2 = (float)bi;  // exact
    // 4-neighbor mean with edge replication
    int up = ain[p - (y > 0 ? WW : 0)];
    int dn = ain[p + (y < HH - 1 ? WW : 0)];
    int lf = ain[p - (x > 0 ? 1 : 0)];
    int rt = ain[p + (x < WW - 1 ? 1 : 0)];
    float nb = (float)(((up + dn) + lf) + rt) * 0.25f;     // exact in f32
    float pair = 50.0f * ((2.0f * nb) - 1.0f);             // exact in f32
    float t0 = i0 - f0, t1 = i1 - f1, t2 = i2 - f2;
    float df = ((t0 * t0) + (t1 * t1)) + (t2 * t2);
    float u0 = i0 - g0, u1 = i1 - g1, u2 = i2 - g2;
    float db = ((u0 * u0) + (u1 * u1)) + (u2 * u2);
    float score = (db - df) + pair;
    int a;
    if (is_center(y, x)) a = 1;           // fixed FG
    else if (is_border(y, x)) a = 0;      // fixed BG
    else a = (score > 0.0f) ? 1 : 0;
    aout[p] = (uint8_t)a;
    if (finalIter) out[p] = (float)a;
    a0 += ri * a; a1 += gi * a; a2 += bi * a; a3 += a;
  }
  __shared__ int red2[256][4];
  red2[tid][0] = a0; red2[tid][1] = a1; red2[tid][2] = a2; red2[tid][3] = a3;
  __syncthreads();
  for (int s = 128; s >= 1; s >>= 1) {
    if (tid < s) {
#pragma unroll
      for (int j = 0; j < 4; j++) red2[tid][j] += red2[tid + s][j];
    }
    __syncthreads();
  }
  if (tid == 0) slotOut[blk] = make_int4(red2[0][0], red2[0][1], red2[0][2], red2[0][3]);
}

extern "C" void kernel_launch(void* const* d_in, const int* in_sizes, int n_in,
                              void* d_out, int out_size, void* d_ws, size_t ws_size,
                              hipStream_t stream) {
  const float* feat = (const float*)d_in[0];   // (2,256,512,512) f32
  const int*   mask = (const int*)d_in[1];     // (2,512,512) i32
  float* out = (float*)d_out;                  // (2,512,512) f32

  // ws layout (~3.1 MB total; fully rewritten each launch, poison-safe):
  char* ws = (char*)d_ws;
  uint8_t*  aA     = (uint8_t*)(ws);                 // 524288
  uint8_t*  aB     = (uint8_t*)(ws + 524288);        // 524288
  float2*   mm     = (float2*)(ws + 1048576);        // 256 * 8B   = 2048
  int4*     totals = (int4*)(ws + 1050624);          // 256 * 16B  = 4096
  int4*     slots  = (int4*)(ws + 1054720);          // 6*256*16B  = 24576
  uint32_t* packed = (uint32_t*)(ws + 1079296);      // 524288 * 4B = 2 MB

  k_minmax<<<256, 256, 0, stream>>>(feat, mm);
  k_init<<<256, 256, 0, stream>>>(feat, mask, mm, packed, aA, totals, slots /*slot0*/);

  uint8_t* ain = aA;
  uint8_t* aout_buf = aB;
  for (int k = 0; k < 5; k++) {
    k_relabel<<<256, 256, 0, stream>>>(packed, ain, aout_buf, totals,
                                       slots + (size_t)k * 256,
                                       slots + (size_t)(k + 1) * 256,
                                       out, (k == 4) ? 1 : 0);
    uint8_t* tmp = ain; ain = aout_buf; aout_buf = tmp;
  }
}